// Round 1
// baseline (853.056 us; speedup 1.0000x reference)
//
#include <hip/hip_runtime.h>
#include <math.h>

#define T 8192
#define B 8
#define CIN 32
#define COUT 32
#define HID 64
#define NTH 256
#define FT 4

__device__ inline float2 cmul(float2 a, float2 b){
    return make_float2(a.x*b.x - a.y*b.y, a.x*b.y + a.y*b.x);
}

__device__ inline float gelu_exact(float x){
    return 0.5f*x*(1.0f + erff(x*0.70710678118654752440f));
}

// Forward radix-2 DIF FFT: natural-order input, bit-reversed-order output.
// Twiddle e^{-i*pi*j/m}. 13 stages, 4096 butterflies/stage, 256 threads.
__device__ void fft_dif(float2* s, int tid){
    for (int m = T/2; m >= 1; m >>= 1){
        float am = -3.14159265358979323846f / (float)m;
        for (int q = tid; q < T/2; q += NTH){
            int j  = q & (m-1);
            int p0 = ((q & ~(m-1)) << 1) | j;
            int p1 = p0 + m;
            float2 a = s[p0], b = s[p1];
            float2 su = make_float2(a.x+b.x, a.y+b.y);
            float2 di = make_float2(a.x-b.x, a.y-b.y);
            float ang = am * (float)j;
            float sn, cs;
            sincosf(ang, &sn, &cs);
            s[p0] = su;
            s[p1] = cmul(di, make_float2(cs, sn));
        }
        __syncthreads();
    }
}

// Inverse radix-2 DIT FFT: bit-reversed-order input, natural-order output.
// Twiddle e^{+i*pi*j/m}. Result unnormalized (divide by T afterwards).
__device__ void fft_dit_inv(float2* s, int tid){
    for (int m = 1; m <= T/2; m <<= 1){
        float am = 3.14159265358979323846f / (float)m;
        for (int q = tid; q < T/2; q += NTH){
            int j  = q & (m-1);
            int p0 = ((q & ~(m-1)) << 1) | j;
            int p1 = p0 + m;
            float2 a = s[p0], b = s[p1];
            float ang = am * (float)j;
            float sn, cs;
            sincosf(ang, &sn, &cs);
            float2 t2 = cmul(b, make_float2(cs, sn));
            s[p0] = make_float2(a.x+t2.x, a.y+t2.y);
            s[p1] = make_float2(a.x-t2.x, a.y-t2.y);
        }
        __syncthreads();
    }
}

// Kernel 1: MLP hidden state. H[h*T + t] = gelu(gelu(pos*w1+b1) @ w2 + b2)
__global__ void mlp_hidden(const float* __restrict__ w1, const float* __restrict__ b1,
                           const float* __restrict__ w2, const float* __restrict__ b2,
                           float* __restrict__ H){
    __shared__ float sw1[HID], sb1[HID], sw2[HID*HID], sb2[HID];
    int tid = threadIdx.x;
    for (int i = tid; i < HID; i += blockDim.x){ sw1[i]=w1[i]; sb1[i]=b1[i]; sb2[i]=b2[i]; }
    for (int i = tid; i < HID*HID; i += blockDim.x) sw2[i]=w2[i];
    __syncthreads();
    int t = blockIdx.x*blockDim.x + tid;
    float pos = (float)t / (float)(T-1);
    float h1[HID];
    #pragma unroll
    for (int h = 0; h < HID; ++h) h1[h] = gelu_exact(pos*sw1[h] + sb1[h]);
    for (int h = 0; h < HID; ++h){
        float acc = sb2[h];
        #pragma unroll
        for (int k = 0; k < HID; ++k) acc += h1[k]*sw2[k*HID + h];
        H[h*T + t] = gelu_exact(acc);
    }
}

// Kernel 2: forward FFT of x signals. One block per (b,i).
__global__ void fft_x_kernel(const float* __restrict__ x, float2* __restrict__ Xf){
    __shared__ float2 s[T];
    int sig = blockIdx.x;                   // b*CIN + i
    int tid = threadIdx.x;
    const float* xp = x + (size_t)sig*T;
    for (int t = tid; t < T; t += NTH) s[t] = make_float2(xp[t], 0.0f);
    __syncthreads();
    fft_dif(s, tid);
    float2* op = Xf + (size_t)sig*T;
    for (int t = tid; t < T; t += NTH) op[t] = s[t];
}

// Kernel 3: filter generation (w3 projection fused) + forward FFT. One block per (o,i).
__global__ void fft_filt_kernel(const float* __restrict__ H, const float* __restrict__ w3,
                                const float* __restrict__ b3, float2* __restrict__ Ff){
    __shared__ float2 s[T];
    int sig = blockIdx.x;                   // o*CIN + i == column index in w3
    int tid = threadIdx.x;
    // column of w3 is block-uniform -> scalar-cached loads, hoisted out of t-loop
    float wc[HID];
    #pragma unroll
    for (int h = 0; h < HID; ++h) wc[h] = w3[h*(CIN*COUT) + sig];
    float bv = b3[sig];
    for (int t = tid; t < T; t += NTH){
        float acc = bv;
        #pragma unroll
        for (int h = 0; h < HID; ++h) acc += H[h*T + t]*wc[h];
        s[t] = make_float2(acc, 0.0f);
    }
    __syncthreads();
    fft_dif(s, tid);
    float2* op = Ff + (size_t)sig*T;
    for (int t = tid; t < T; t += NTH) op[t] = s[t];
}

// Kernel 4: per-frequency contraction Y[b,o,f] = sum_i X[b,i,f]*F[o,i,f]
// (frequencies in bit-reversed order — consistent elementwise, so it's fine).
__global__ void contract_kernel(const float2* __restrict__ Xf, const float2* __restrict__ Ff,
                                float2* __restrict__ Yf){
    __shared__ float2 Xs[B*CIN*FT];     // 1024 * 8B = 8 KB
    __shared__ float2 Fs[COUT*CIN*FT];  // 4096 * 8B = 32 KB
    int f0 = blockIdx.x * FT;
    int tid = threadIdx.x;
    for (int e = tid; e < B*CIN*FT; e += NTH){
        int sg = e >> 2, ff = e & 3;
        Xs[e] = Xf[(size_t)sg*T + f0 + ff];
    }
    for (int e = tid; e < COUT*CIN*FT; e += NTH){
        int sg = e >> 2, ff = e & 3;
        Fs[e] = Ff[(size_t)sg*T + f0 + ff];
    }
    __syncthreads();
    for (int u = tid; u < B*COUT*FT; u += NTH){
        int ff = u & 3;
        int o  = (u >> 2) & 31;
        int b  = u >> 7;
        float2 acc = make_float2(0.0f, 0.0f);
        #pragma unroll
        for (int i = 0; i < CIN; ++i){
            float2 xv = Xs[((b*CIN + i) << 2) | ff];
            float2 fv = Fs[((o*CIN + i) << 2) | ff];
            acc.x += xv.x*fv.x - xv.y*fv.y;
            acc.y += xv.x*fv.y + xv.y*fv.x;
        }
        Yf[((size_t)(b*COUT + o))*T + f0 + ff] = acc;
    }
}

// Kernel 5: inverse FFT, scale 1/T, add bias, write real part. One block per (b,o).
__global__ void ifft_out_kernel(const float2* __restrict__ Yf, const float* __restrict__ bias,
                                float* __restrict__ out){
    __shared__ float2 s[T];
    int sig = blockIdx.x;                   // b*COUT + o
    int o   = sig & (COUT-1);
    int tid = threadIdx.x;
    const float2* yp = Yf + (size_t)sig*T;
    for (int t = tid; t < T; t += NTH) s[t] = yp[t];
    __syncthreads();
    fft_dit_inv(s, tid);
    float bv = bias[o];
    const float scale = 1.0f/(float)T;
    float* op = out + (size_t)sig*T;
    for (int t = tid; t < T; t += NTH) op[t] = s[t].x*scale + bv;
}

extern "C" void kernel_launch(void* const* d_in, const int* in_sizes, int n_in,
                              void* d_out, int out_size, void* d_ws, size_t ws_size,
                              hipStream_t stream){
    const float* x    = (const float*)d_in[0];
    const float* w1   = (const float*)d_in[1];
    const float* b1   = (const float*)d_in[2];
    const float* w2   = (const float*)d_in[3];
    const float* b2   = (const float*)d_in[4];
    const float* w3   = (const float*)d_in[5];
    const float* b3   = (const float*)d_in[6];
    const float* bias = (const float*)d_in[7];
    float* out = (float*)d_out;

    char* ws = (char*)d_ws;
    float*  H  = (float*)ws;                                        // HID*T floats (2 MB)
    float2* Xf = (float2*)(ws + (size_t)HID*T*sizeof(float));       // B*CIN*T cplx (16 MB)
    float2* Ff = (float2*)((char*)Xf + (size_t)B*CIN*T*sizeof(float2));   // 64 MB
    float2* Yf = (float2*)((char*)Ff + (size_t)COUT*CIN*T*sizeof(float2));// 16 MB

    hipLaunchKernelGGL(mlp_hidden,      dim3(T/NTH),     dim3(NTH), 0, stream, w1, b1, w2, b2, H);
    hipLaunchKernelGGL(fft_x_kernel,    dim3(B*CIN),     dim3(NTH), 0, stream, x, Xf);
    hipLaunchKernelGGL(fft_filt_kernel, dim3(COUT*CIN),  dim3(NTH), 0, stream, H, w3, b3, Ff);
    hipLaunchKernelGGL(contract_kernel, dim3(T/FT),      dim3(NTH), 0, stream, Xf, Ff, Yf);
    hipLaunchKernelGGL(ifft_out_kernel, dim3(B*COUT),    dim3(NTH), 0, stream, Yf, bias, out);
}

// Round 2
// 293.633 us; speedup vs baseline: 2.9052x; 2.9052x over previous
//
#include <hip/hip_runtime.h>
#include <math.h>

#define T 8192
#define B 8
#define CIN 32
#define COUT 32
#define HID 64
#define NTH 256
#define FTH 512
#define FT 4
#define GOI 64
#define GC 128

__device__ inline float2 cmul(float2 a, float2 b){
    return make_float2(a.x*b.x - a.y*b.y, a.x*b.y + a.y*b.x);
}

__device__ inline float gelu_exact(float x){
    return 0.5f*x*(1.0f + erff(x*0.70710678118654752440f));
}

// Twiddle table: tw[k] = e^{-2*pi*i*k/T}, k < T/2 (32 KB, L1/L2-resident).
__global__ __launch_bounds__(256) void tw_init(float2* __restrict__ tw){
    int k = blockIdx.x*blockDim.x + threadIdx.x;   // 0..4095
    float ang = -6.28318530717958647692f * (float)k / (float)T;
    float s, c;
    sincosf(ang, &s, &c);
    tw[k] = make_float2(c, s);
}

// Forward radix-2 DIF: natural in, bit-reversed out. Stage-m twiddle e^{-i*pi*j/m} = tw[j<<sh].
__device__ void fft_dif(float2* s, const float2* __restrict__ tw, int tid){
    int sh = 0;
    for (int m = T/2; m >= 1; m >>= 1, ++sh){
        for (int q = tid; q < T/2; q += FTH){
            int j  = q & (m-1);
            int p0 = ((q & ~(m-1)) << 1) | j;
            int p1 = p0 + m;
            float2 a = s[p0], b = s[p1];
            float2 w = tw[j << sh];
            float2 su = make_float2(a.x+b.x, a.y+b.y);
            float2 di = make_float2(a.x-b.x, a.y-b.y);
            s[p0] = su;
            s[p1] = cmul(di, w);
        }
        __syncthreads();
    }
}

// Inverse radix-2 DIT: bit-reversed in, natural out, conjugate twiddles, unnormalized.
__device__ void fft_dit_inv(float2* s, const float2* __restrict__ tw, int tid){
    int sh = 12;
    for (int m = 1; m <= T/2; m <<= 1, --sh){
        for (int q = tid; q < T/2; q += FTH){
            int j  = q & (m-1);
            int p0 = ((q & ~(m-1)) << 1) | j;
            int p1 = p0 + m;
            float2 a = s[p0], b = s[p1];
            float2 w = tw[j << sh];
            float2 wc = make_float2(w.x, -w.y);
            float2 t2 = cmul(b, wc);
            s[p0] = make_float2(a.x+t2.x, a.y+t2.y);
            s[p1] = make_float2(a.x-t2.x, a.y-t2.y);
        }
        __syncthreads();
    }
}

// Kernel 1: MLP hidden state H[h*T + t]
__global__ __launch_bounds__(256) void mlp_hidden(const float* __restrict__ w1, const float* __restrict__ b1,
                           const float* __restrict__ w2, const float* __restrict__ b2,
                           float* __restrict__ H){
    __shared__ float sw1[HID], sb1[HID], sw2[HID*HID], sb2[HID];
    int tid = threadIdx.x;
    for (int i = tid; i < HID; i += blockDim.x){ sw1[i]=w1[i]; sb1[i]=b1[i]; sb2[i]=b2[i]; }
    for (int i = tid; i < HID*HID; i += blockDim.x) sw2[i]=w2[i];
    __syncthreads();
    int t = blockIdx.x*blockDim.x + tid;
    float pos = (float)t / (float)(T-1);
    float h1[HID];
    #pragma unroll
    for (int h = 0; h < HID; ++h) h1[h] = gelu_exact(pos*sw1[h] + sb1[h]);
    for (int h = 0; h < HID; ++h){
        float acc = sb2[h];
        #pragma unroll
        for (int k = 0; k < HID; ++k) acc += h1[k]*sw2[k*HID + h];
        H[h*T + t] = gelu_exact(acc);
    }
}

// Kernel 2: forward FFT of x. One block per (b,i).
__global__ __launch_bounds__(FTH) void fft_x_kernel(const float* __restrict__ x, const float2* __restrict__ tw,
                                                    float2* __restrict__ Xf){
    __shared__ float2 s[T];
    int sig = blockIdx.x;
    int tid = threadIdx.x;
    const float* xp = x + (size_t)sig*T;
    for (int t = tid; t < T; t += FTH) s[t] = make_float2(xp[t], 0.0f);
    __syncthreads();
    fft_dif(s, tw, tid);
    float2* op = Xf + (size_t)sig*T;
    for (int t = tid; t < T; t += FTH) op[t] = s[t];
}

// Kernel 3: forward FFT of the 64 hidden channels. One block per h.
__global__ __launch_bounds__(FTH) void fft_h_kernel(const float* __restrict__ H, const float2* __restrict__ tw,
                                                    float2* __restrict__ Hf){
    __shared__ float2 s[T];
    int h = blockIdx.x;
    int tid = threadIdx.x;
    const float* hp = H + (size_t)h*T;
    for (int t = tid; t < T; t += FTH) s[t] = make_float2(hp[t], 0.0f);
    __syncthreads();
    fft_dif(s, tw, tid);
    float2* op = Hf + (size_t)h*T;
    for (int t = tid; t < T; t += FTH) op[t] = s[t];
}

// Kernel 4: frequency-domain filter GEMM.
// F[oi, c] = sum_h w3[h,oi] * Hf[h, c]  (c = interleaved re/im real column, 2T of them)
// + DC correction: F[oi, c==0] += T*b3[oi]  (bit-reversed position 0 == frequency 0, real part)
__global__ __launch_bounds__(256) void fgemm(const float* __restrict__ w3, const float* __restrict__ b3,
                                             const float* __restrict__ Hf, float* __restrict__ Ff){
    __shared__ float As[HID][GOI];       // w3 tile [k][oi]
    __shared__ float Bs[HID][GC+4];      // Hf tile [k][c]
    int tid = threadIdx.x;
    int oi0 = blockIdx.x * GOI;
    int c0  = blockIdx.y * GC;
    for (int e = tid; e < HID*GOI; e += 256){
        int k = e >> 6, oi = e & 63;
        As[k][oi] = w3[k*(CIN*COUT) + oi0 + oi];
    }
    for (int e = tid; e < HID*GC; e += 256){
        int k = e >> 7, c = e & 127;
        Bs[k][c] = Hf[(size_t)k*(2*T) + c0 + c];
    }
    __syncthreads();
    int tx = tid & 15, ty = tid >> 4;    // tx: c-group (8 wide), ty: oi-group (4 wide)
    float acc[4][8];
    #pragma unroll
    for (int u = 0; u < 4; ++u)
        #pragma unroll
        for (int v = 0; v < 8; ++v) acc[u][v] = 0.0f;
    for (int k = 0; k < HID; ++k){
        float4 av = *(const float4*)&As[k][ty*4];
        float4 b0 = *(const float4*)&Bs[k][tx*8];
        float4 b1 = *(const float4*)&Bs[k][tx*8 + 4];
        float a[4] = {av.x, av.y, av.z, av.w};
        float bv[8] = {b0.x,b0.y,b0.z,b0.w,b1.x,b1.y,b1.z,b1.w};
        #pragma unroll
        for (int u = 0; u < 4; ++u)
            #pragma unroll
            for (int v = 0; v < 8; ++v) acc[u][v] += a[u]*bv[v];
    }
    #pragma unroll
    for (int u = 0; u < 4; ++u){
        int oi = oi0 + ty*4 + u;
        float dc = (float)T * b3[oi];
        float* op = Ff + (size_t)oi*(2*T) + c0 + tx*8;
        #pragma unroll
        for (int v = 0; v < 8; ++v){
            float val = acc[u][v];
            if (c0 + tx*8 + v == 0) val += dc;
            op[v] = val;
        }
    }
}

// Kernel 5: per-frequency contraction Y[b,o,f] = sum_i X[b,i,f]*F[oi,f]
__global__ __launch_bounds__(256) void contract_kernel(const float2* __restrict__ Xf, const float2* __restrict__ Ff,
                                float2* __restrict__ Yf){
    __shared__ float2 Xs[B*CIN*FT];
    __shared__ float2 Fs[COUT*CIN*FT];
    int f0 = blockIdx.x * FT;
    int tid = threadIdx.x;
    for (int e = tid; e < B*CIN*FT; e += NTH){
        int sg = e >> 2, ff = e & 3;
        Xs[e] = Xf[(size_t)sg*T + f0 + ff];
    }
    for (int e = tid; e < COUT*CIN*FT; e += NTH){
        int sg = e >> 2, ff = e & 3;
        Fs[e] = Ff[(size_t)sg*T + f0 + ff];
    }
    __syncthreads();
    for (int u = tid; u < B*COUT*FT; u += NTH){
        int ff = u & 3;
        int o  = (u >> 2) & 31;
        int b  = u >> 7;
        float2 acc = make_float2(0.0f, 0.0f);
        #pragma unroll
        for (int i = 0; i < CIN; ++i){
            float2 xv = Xs[((b*CIN + i) << 2) | ff];
            float2 fv = Fs[((o*CIN + i) << 2) | ff];
            acc.x += xv.x*fv.x - xv.y*fv.y;
            acc.y += xv.x*fv.y + xv.y*fv.x;
        }
        Yf[((size_t)(b*COUT + o))*T + f0 + ff] = acc;
    }
}

// Kernel 6: inverse FFT + 1/T + bias. One block per (b,o).
__global__ __launch_bounds__(FTH) void ifft_out_kernel(const float2* __restrict__ Yf, const float2* __restrict__ tw,
                                const float* __restrict__ bias, float* __restrict__ out){
    __shared__ float2 s[T];
    int sig = blockIdx.x;
    int o   = sig & (COUT-1);
    int tid = threadIdx.x;
    const float2* yp = Yf + (size_t)sig*T;
    for (int t = tid; t < T; t += FTH) s[t] = yp[t];
    __syncthreads();
    fft_dit_inv(s, tw, tid);
    float bv = bias[o];
    const float scale = 1.0f/(float)T;
    float* op = out + (size_t)sig*T;
    for (int t = tid; t < T; t += FTH) op[t] = s[t].x*scale + bv;
}

extern "C" void kernel_launch(void* const* d_in, const int* in_sizes, int n_in,
                              void* d_out, int out_size, void* d_ws, size_t ws_size,
                              hipStream_t stream){
    const float* x    = (const float*)d_in[0];
    const float* w1   = (const float*)d_in[1];
    const float* b1   = (const float*)d_in[2];
    const float* w2   = (const float*)d_in[3];
    const float* b2   = (const float*)d_in[4];
    const float* w3   = (const float*)d_in[5];
    const float* b3   = (const float*)d_in[6];
    const float* bias = (const float*)d_in[7];
    float* out = (float*)d_out;

    // Workspace layout (96.03 MB total; H/Hf alias Yf's region — dead before contract writes Yf):
    char* ws = (char*)d_ws;
    float2* Xf = (float2*)ws;                                  // 16 MB  [0, 16M)
    float2* Ff = (float2*)(ws + (size_t)16*1024*1024);         // 64 MB  [16M, 80M)
    float2* Yf = (float2*)(ws + (size_t)80*1024*1024);         // 16 MB  [80M, 96M)
    float*  H  = (float*)Yf;                                   // 2 MB   (alias, dead after fft_h)
    float2* Hf = (float2*)(ws + (size_t)82*1024*1024);         // 4 MB   (alias, dead after fgemm)
    float2* tws= (float2*)(ws + (size_t)96*1024*1024);         // 32 KB

    hipLaunchKernelGGL(tw_init,        dim3(16),          dim3(256), 0, stream, tws);
    hipLaunchKernelGGL(mlp_hidden,     dim3(T/NTH),       dim3(NTH), 0, stream, w1, b1, w2, b2, H);
    hipLaunchKernelGGL(fft_x_kernel,   dim3(B*CIN),       dim3(FTH), 0, stream, x, tws, Xf);
    hipLaunchKernelGGL(fft_h_kernel,   dim3(HID),         dim3(FTH), 0, stream, H, tws, Hf);
    hipLaunchKernelGGL(fgemm,          dim3(1024/GOI, 2*T/GC), dim3(256), 0, stream, w3, b3, (const float*)Hf, (float*)Ff);
    hipLaunchKernelGGL(contract_kernel,dim3(T/FT),        dim3(NTH), 0, stream, Xf, Ff, Yf);
    hipLaunchKernelGGL(ifft_out_kernel,dim3(B*COUT),      dim3(FTH), 0, stream, Yf, tws, bias, out);
}

// Round 3
// 181.289 us; speedup vs baseline: 4.7055x; 1.6197x over previous
//
#include <hip/hip_runtime.h>
#include <math.h>

#define T 8192
#define B 8
#define CIN 32
#define COUT 32
#define HID 64
#define FT 4

__device__ inline float2 cadd(float2 a, float2 b){ return make_float2(a.x+b.x, a.y+b.y); }
__device__ inline float2 csub(float2 a, float2 b){ return make_float2(a.x-b.x, a.y-b.y); }
__device__ inline float2 cmul(float2 a, float2 b){ return make_float2(a.x*b.x - a.y*b.y, a.x*b.y + a.y*b.x); }
__device__ inline float2 cmulc(float2 a, float2 b){ // a * conj(b)
    return make_float2(a.x*b.x + a.y*b.y, a.y*b.x - a.x*b.y); }
__device__ inline int swz(int p){ return p ^ ((p >> 5) & 31); }

__device__ inline float gelu_exact(float x){
    return 0.5f*x*(1.0f + erff(x*0.70710678118654752440f));
}

// Twiddle table: tw[k] = e^{-2*pi*i*k/T}, k < T/2
__global__ __launch_bounds__(256) void tw_init(float2* __restrict__ tw){
    int k = blockIdx.x*blockDim.x + threadIdx.x;   // 0..4095
    float ang = -6.28318530717958647692f * (float)k / (float)T;
    float s, c;
    sincosf(ang, &s, &c);
    tw[k] = make_float2(c, s);
}

// ---------- register-blocked FFT pieces (16 points / thread, 512 threads) ----------
// Forward DIF group: 4 stages, distances d=8,4,2,1 in local index space.
// Global stage m = S*d, twiddle index j = r + S*(k mod d), applied as tw[j << sh].
template<int S, int SH0>
__device__ inline void dif_group(float2 q[16], int r, const float2* __restrict__ tw){
    #pragma unroll
    for (int st = 0; st < 4; ++st){
        const int d = 8 >> st;
        const int sh = SH0 + st;
        #pragma unroll
        for (int k = 0; k < 8; ++k){
            const int jd = k & (d-1);
            const int lo = ((k & ~(d-1)) << 1) | jd;
            const int hi = lo + d;
            float2 w = tw[(r + S*jd) << sh];
            float2 a = q[lo], b = q[hi];
            q[lo] = cadd(a, b);
            q[hi] = cmul(csub(a, b), w);
        }
    }
}

// Inverse DIT group: 4 stages, d=1,2,4,8 ascending, conjugated twiddles.
template<int S, int SH0>
__device__ inline void dit_group(float2 q[16], int r, const float2* __restrict__ tw){
    #pragma unroll
    for (int st = 0; st < 4; ++st){
        const int d = 1 << st;
        const int sh = SH0 - st;
        #pragma unroll
        for (int k = 0; k < 8; ++k){
            const int jd = k & (d-1);
            const int lo = ((k & ~(d-1)) << 1) | jd;
            const int hi = lo + d;
            float2 w = tw[(r + S*jd) << sh];
            float2 a = q[lo];
            float2 t2 = cmulc(q[hi], w);
            q[lo] = cadd(a, t2);
            q[hi] = csub(a, t2);
        }
    }
}

__device__ inline void lds_store16(float* sRe, float* sIm, const float2* q, int base, int S){
    #pragma unroll
    for (int l = 0; l < 16; ++l){ int a = swz(base + S*l); sRe[a] = q[l].x; sIm[a] = q[l].y; }
}
__device__ inline void lds_load16(const float* sRe, const float* sIm, float2* q, int base, int S){
    #pragma unroll
    for (int l = 0; l < 16; ++l){ int a = swz(base + S*l); q[l] = make_float2(sRe[a], sIm[a]); }
}

// Forward FFT of a real row: natural in -> bit-reversed-order complex out.
// Stage groups: {4096,2048,1024,512} regs, {256..32}, {16..2}, m=1 fused into writeout.
__global__ __launch_bounds__(512) void fft_fwd_kernel(const float* __restrict__ src,
        const float2* __restrict__ tw, float2* __restrict__ dst){
    __shared__ float sRe[T], sIm[T];
    const int t = threadIdx.x;
    const int sig = blockIdx.x;
    const float* sp = src + (size_t)sig*T;
    float2 q[16];
    #pragma unroll
    for (int l = 0; l < 16; ++l) q[l] = make_float2(sp[t + 512*l], 0.0f);
    dif_group<512,0>(q, t, tw);
    lds_store16(sRe, sIm, q, t, 512);
    __syncthreads();
    {
        const int base = ((t>>5)<<9) | (t&31);
        lds_load16(sRe, sIm, q, base, 32);
        dif_group<32,4>(q, t&31, tw);
        lds_store16(sRe, sIm, q, base, 32);
    }
    __syncthreads();
    {
        const int base = ((t>>1)<<5) | (t&1);
        lds_load16(sRe, sIm, q, base, 2);
        dif_group<2,8>(q, t&1, tw);
        lds_store16(sRe, sIm, q, base, 2);
    }
    __syncthreads();
    // final m=1 stage (tw[0]=1) fused with coalesced writeout
    float2* dp = dst + (size_t)sig*T;
    #pragma unroll
    for (int l = 0; l < 16; ++l){
        const int c = t + 512*l;
        const int e = c & ~1;
        float2 a = make_float2(sRe[swz(e)],   sIm[swz(e)]);
        float2 b = make_float2(sRe[swz(e|1)], sIm[swz(e|1)]);
        dp[c] = (c & 1) ? csub(a, b) : cadd(a, b);
    }
}

// Inverse FFT: bit-reversed-order complex in -> natural real out (*1/T + bias).
// Groups: {1,2,4,8}, {16..128}, {256..2048}, m=4096 fused into output.
__global__ __launch_bounds__(512) void ifft_out_kernel(const float2* __restrict__ Yf,
        const float2* __restrict__ tw, const float* __restrict__ bias, float* __restrict__ out){
    __shared__ float sRe[T], sIm[T];
    const int t = threadIdx.x;
    const int sig = blockIdx.x;
    const float2* yp = Yf + (size_t)sig*T;
    #pragma unroll
    for (int l = 0; l < 16; ++l){
        const int c = t + 512*l;
        float2 v = yp[c];
        const int a = swz(c);
        sRe[a] = v.x; sIm[a] = v.y;
    }
    __syncthreads();
    float2 q[16];
    {
        const int base = t << 4;
        lds_load16(sRe, sIm, q, base, 1);
        dit_group<1,12>(q, 0, tw);
        lds_store16(sRe, sIm, q, base, 1);
    }
    __syncthreads();
    {
        const int base = ((t>>4)<<8) | (t&15);
        lds_load16(sRe, sIm, q, base, 16);
        dit_group<16,8>(q, t&15, tw);
        lds_store16(sRe, sIm, q, base, 16);
    }
    __syncthreads();
    {
        const int base = ((t>>8)<<12) | (t&255);
        lds_load16(sRe, sIm, q, base, 256);
        dit_group<256,4>(q, t&255, tw);
        lds_store16(sRe, sIm, q, base, 256);
    }
    __syncthreads();
    lds_load16(sRe, sIm, q, t, 512);
    const int o = sig & (COUT-1);
    const float bv = bias[o];
    const float scale = 1.0f/(float)T;
    float* op = out + (size_t)sig*T;
    #pragma unroll
    for (int l = 0; l < 8; ++l){
        float2 w = tw[t + 512*l];          // m=4096, sh=0
        float2 a = q[l];
        float2 t2 = cmulc(q[l+8], w);
        op[t + 512*l]        = (a.x + t2.x)*scale + bv;
        op[t + 512*l + 4096] = (a.x - t2.x)*scale + bv;
    }
}

// MLP hidden state H[h*T + t]
__global__ __launch_bounds__(256) void mlp_hidden(const float* __restrict__ w1, const float* __restrict__ b1,
                           const float* __restrict__ w2, const float* __restrict__ b2,
                           float* __restrict__ H){
    __shared__ float sw1[HID], sb1[HID], sw2[HID*HID], sb2[HID];
    int tid = threadIdx.x;
    for (int i = tid; i < HID; i += blockDim.x){ sw1[i]=w1[i]; sb1[i]=b1[i]; sb2[i]=b2[i]; }
    for (int i = tid; i < HID*HID; i += blockDim.x) sw2[i]=w2[i];
    __syncthreads();
    int t = blockIdx.x*blockDim.x + tid;
    float pos = (float)t / (float)(T-1);
    float h1[HID];
    #pragma unroll
    for (int h = 0; h < HID; ++h) h1[h] = gelu_exact(pos*sw1[h] + sb1[h]);
    for (int h = 0; h < HID; ++h){
        float acc = sb2[h];
        #pragma unroll
        for (int k = 0; k < HID; ++k) acc += h1[k]*sw2[k*HID + h];
        H[h*T + t] = gelu_exact(acc);
    }
}

// Fused filter-spectrum GEMM + channel contraction, per 4-frequency tile.
// Filt[oi][f] = sum_h w3[h,oi]*Hf[h,f] (+ T*b3[oi] at DC);  Y[b,o,f] = sum_i X[b,i,f]*Filt[o*32+i][f]
__global__ __launch_bounds__(256) void filt_contract(const float* __restrict__ w3,
        const float* __restrict__ b3, const float2* __restrict__ Hf,
        const float2* __restrict__ Xf, float2* __restrict__ Yf){
    __shared__ float2 Xs[B][CIN][FT];        // 8 KB
    __shared__ float2 FiltS[FT][CIN*COUT];   // 32 KB
    const int t = threadIdx.x;
    const int f0 = blockIdx.x * FT;
    // stage X tile: sig = t (0..255 = B*CIN)
    {
        const float2* xp = Xf + (size_t)t*T + f0;
        float2 v0 = xp[0], v1 = xp[1], v2 = xp[2], v3 = xp[3];
        const int b = t >> 5, i = t & 31;
        Xs[b][i][0] = v0; Xs[b][i][1] = v1; Xs[b][i][2] = v2; Xs[b][i][3] = v3;
    }
    // phase A: filter tile in registers. thread -> (o = t>>3, iset = t&7), 4 oi x 4 f
    const int oi0 = ((t >> 3) << 5) | ((t & 7) << 2);
    float2 acc[4][FT];
    #pragma unroll
    for (int ii = 0; ii < 4; ++ii)
        #pragma unroll
        for (int f = 0; f < FT; ++f) acc[ii][f] = make_float2(0.f, 0.f);
    for (int h = 0; h < HID; ++h){
        const float4 w4 = *(const float4*)(w3 + (size_t)h*(CIN*COUT) + oi0);  // coalesced, L2-resident
        const float2* hp = Hf + (size_t)h*T + f0;                             // block-uniform -> scalar
        float2 h0 = hp[0], h1 = hp[1], h2 = hp[2], h3 = hp[3];
        const float wv[4] = {w4.x, w4.y, w4.z, w4.w};
        #pragma unroll
        for (int ii = 0; ii < 4; ++ii){
            acc[ii][0].x += wv[ii]*h0.x; acc[ii][0].y += wv[ii]*h0.y;
            acc[ii][1].x += wv[ii]*h1.x; acc[ii][1].y += wv[ii]*h1.y;
            acc[ii][2].x += wv[ii]*h2.x; acc[ii][2].y += wv[ii]*h2.y;
            acc[ii][3].x += wv[ii]*h3.x; acc[ii][3].y += wv[ii]*h3.y;
        }
    }
    if (f0 == 0){   // DC correction: bit-reversed position 0 == frequency 0
        #pragma unroll
        for (int ii = 0; ii < 4; ++ii)
            acc[ii][0].x += (float)T * b3[oi0 + ii];
    }
    #pragma unroll
    for (int f = 0; f < FT; ++f)
        #pragma unroll
        for (int ii = 0; ii < 4; ++ii)
            FiltS[f][oi0 + ii] = acc[ii][f];
    __syncthreads();
    // phase B: thread -> (o2 = t>>3, f2 = (t>>1)&3, g = t&1), 4 batches each
    const int o2 = t >> 3, f2 = (t >> 1) & 3, g = t & 1;
    float2 y[4];
    #pragma unroll
    for (int j = 0; j < 4; ++j) y[j] = make_float2(0.f, 0.f);
    #pragma unroll 4
    for (int i0 = 0; i0 < CIN; ++i0){
        const int i = (i0 + o2) & 31;           // rotation breaks bank degeneracy
        const float2 fv = FiltS[f2][(o2 << 5) | i];
        #pragma unroll
        for (int j = 0; j < 4; ++j){
            const float2 xv = Xs[(g << 2) | j][i][f2];
            y[j].x += xv.x*fv.x - xv.y*fv.y;
            y[j].y += xv.x*fv.y + xv.y*fv.x;
        }
    }
    #pragma unroll
    for (int j = 0; j < 4; ++j){
        const int b = (g << 2) | j;
        Yf[((size_t)(b*COUT + o2))*T + f0 + f2] = y[j];
    }
}

extern "C" void kernel_launch(void* const* d_in, const int* in_sizes, int n_in,
                              void* d_out, int out_size, void* d_ws, size_t ws_size,
                              hipStream_t stream){
    const float* x    = (const float*)d_in[0];
    const float* w1   = (const float*)d_in[1];
    const float* b1   = (const float*)d_in[2];
    const float* w2   = (const float*)d_in[3];
    const float* b2   = (const float*)d_in[4];
    const float* w3   = (const float*)d_in[5];
    const float* b3   = (const float*)d_in[6];
    const float* bias = (const float*)d_in[7];
    float* out = (float*)d_out;

    // Workspace: Xf 16MB | Yf 16MB | H 2MB | Hf 4MB | tw 32KB  (~38 MB)
    char* ws = (char*)d_ws;
    float2* Xf = (float2*)ws;
    float2* Yf = (float2*)(ws + (size_t)16*1024*1024);
    float*  H  = (float*) (ws + (size_t)32*1024*1024);
    float2* Hf = (float2*)(ws + (size_t)34*1024*1024);
    float2* tws= (float2*)(ws + (size_t)38*1024*1024);

    hipLaunchKernelGGL(tw_init,         dim3(16),   dim3(256), 0, stream, tws);
    hipLaunchKernelGGL(mlp_hidden,      dim3(T/256),dim3(256), 0, stream, w1, b1, w2, b2, H);
    hipLaunchKernelGGL(fft_fwd_kernel,  dim3(B*CIN),dim3(512), 0, stream, x, tws, Xf);
    hipLaunchKernelGGL(fft_fwd_kernel,  dim3(HID),  dim3(512), 0, stream, H, tws, Hf);
    hipLaunchKernelGGL(filt_contract,   dim3(T/FT), dim3(256), 0, stream, w3, b3, Hf, Xf, Yf);
    hipLaunchKernelGGL(ifft_out_kernel, dim3(B*COUT), dim3(512), 0, stream, Yf, tws, bias, out);
}